// Round 9
// baseline (3197.649 us; speedup 1.0000x reference)
//
#include <hip/hip_runtime.h>
#include <hip/hip_bf16.h>
#include <stdint.h>

#define GRIDN 48
#define F 2304
#define C 128
#define H 8
#define DH 16
#define NB 2          // batch (meshes)
#define WID 256
#define NLV 49        // BFS levels for GRID=48, anchor at (24,24)

#define NFB 144       // flood blocks (72 per mesh), all co-resident
#define NFBM 72       // flood blocks per mesh
#define NFT 512       // threads per flood block; 2 halves per (q,h) state
#define QPB 32        // queries owned per block (pos = s*NFBM + bi)
#define MAXRING 96    // max BFS ring size (94) padded
#define CHUNK_MIN 128 // min suffix keys per pacing round

typedef __hip_bfloat16 bf16;

__device__ __forceinline__ float b2f(bf16 v) { return __bfloat162float(v); }

__device__ __forceinline__ unsigned short f2bu(float f) {
    __hip_bfloat16 b = __float2bfloat16(f);
    return *(unsigned short*)&b;
}

#define LOF(u) __uint_as_float((u) << 16)
#define HIF(u) __uint_as_float((u) & 0xffff0000u)

// ---------------------------------------------------------------- K-1: input dtype detector
__global__ void k_detect(const void* __restrict__ x, int* __restrict__ flag) {
    __shared__ int bad;
    if (threadIdx.x == 0) bad = 0;
    __syncthreads();
    const bf16* xb = (const bf16*)x;
    int insane = 0;
    #pragma unroll
    for (int i = 0; i < 8; ++i) {
        float v = b2f(xb[threadIdx.x * 8 + i]);
        if (!(fabsf(v) < 1e10f)) insane = 1;
    }
    if (insane) atomicOr(&bad, 1);
    __syncthreads();
    if (threadIdx.x == 0) *flag = bad;
}

// ---------------------------------------------------------------- K0: ring permutation tables (+ zero barrier counter)
__global__ void k_perm(int* __restrict__ permIdx, int* __restrict__ invPerm,
                       int* __restrict__ startOfPos, int* __restrict__ levOfPos,
                       int* __restrict__ ringStart, int* __restrict__ gcount) {
    __shared__ int cnt[NLV], start[NLV], rs0[NLV];
    int t = threadIdx.x;
    if (t < NLV) cnt[t] = 0;
    if (t == 0) *gcount = 0;
    __syncthreads();
    for (int f = t; f < F; f += 256) {
        int d = abs(f / GRIDN - GRIDN / 2) + abs(f % GRIDN - GRIDN / 2);
        atomicAdd(&cnt[d], 1);
    }
    __syncthreads();
    if (t == 0) {
        int s = 0;
        for (int l = 0; l < NLV; ++l) { start[l] = s; rs0[l] = s; ringStart[l] = s; s += cnt[l]; }
        ringStart[NLV] = s;
    }
    __syncthreads();
    for (int f = t; f < F; f += 256) {
        int d = abs(f / GRIDN - GRIDN / 2) + abs(f % GRIDN - GRIDN / 2);
        int p = atomicAdd(&start[d], 1);
        permIdx[f] = p;
        invPerm[p] = f;
        startOfPos[p] = rs0[d];
        levOfPos[p] = d;
    }
}

// ---------------------------------------------------------------- K0b: weights -> fp32
struct WSeg { const void* src; int off; int cnt; };
struct WSegs { WSeg s[14]; };

__global__ void k_convert(WSegs segs, const int* __restrict__ flag,
                          float* __restrict__ dst, int total) {
    int i = blockIdx.x * blockDim.x + threadIdx.x;
    if (i >= total) return;
    bool f32 = (*flag != 0);
    #pragma unroll 1
    for (int j = 0; j < 14; ++j) {
        int off = segs.s[j].off, cnt = segs.s[j].cnt;
        if (i >= off && i < off + cnt) {
            int k = i - off;
            dst[i] = f32 ? ((const float*)segs.s[j].src)[k]
                         : b2f(((const bf16*)segs.s[j].src)[k]);
            return;
        }
    }
}

// ---------------------------------------------------------------- K1: x[B,C,F] -> cur[B,F,C]
__global__ void k_transpose_in(const void* __restrict__ x, const int* __restrict__ flag,
                               float* __restrict__ cur) {
    __shared__ float tile[32][33];
    bool f32 = (*flag != 0);
    int b = blockIdx.z;
    int f0 = blockIdx.x * 32, c0 = blockIdx.y * 32;
    int tx = threadIdx.x, ty = threadIdx.y;
    #pragma unroll
    for (int i = 0; i < 4; ++i) {
        int c = c0 + ty + i * 8;
        size_t idx = ((size_t)b * C + c) * F + f0 + tx;
        tile[ty + i * 8][tx] = f32 ? ((const float*)x)[idx] : b2f(((const bf16*)x)[idx]);
    }
    __syncthreads();
    #pragma unroll
    for (int i = 0; i < 4; ++i) {
        int f = f0 + ty + i * 8;
        cur[((size_t)b * F + f) * C + c0 + tx] = tile[tx][ty + i * 8];
    }
}

// ---------------------------------------------------------------- K2: projections; kh0p/vh0p = INITIAL K/V
// packed bf16, pos-major [mesh][pos][64] (u32 = ch pair 2u,2u+1); ring-permuted pos.
__global__ __launch_bounds__(128) void k_proj_init(
        const float* __restrict__ cur, const int* __restrict__ permIdx,
        const float* __restrict__ Wq, const float* __restrict__ Wk, const float* __restrict__ Wv,
        float* __restrict__ qh, unsigned int* __restrict__ kh0p, unsigned int* __restrict__ vh0p) {
    __shared__ float rows[8][C];
    int r0 = blockIdx.x * 8;
    int tid = threadIdx.x;
    #pragma unroll
    for (int r = 0; r < 8; ++r) rows[r][tid] = cur[(size_t)(r0 + r) * C + tid];
    __syncthreads();
    float aq[8], ak[8], av[8];
    #pragma unroll
    for (int r = 0; r < 8; ++r) { aq[r] = 0.f; ak[r] = 0.f; av[r] = 0.f; }
    for (int k = 0; k < C; ++k) {
        float wq = Wq[k * C + tid];
        float wk = Wk[k * C + tid];
        float wv = Wv[k * C + tid];
        #pragma unroll
        for (int r = 0; r < 8; ++r) {
            float xv = rows[r][k];
            aq[r] = fmaf(xv, wq, aq[r]);
            ak[r] = fmaf(xv, wk, ak[r]);
            av[r] = fmaf(xv, wv, av[r]);
        }
    }
    const float scale = 0.25f;
    #pragma unroll
    for (int r = 0; r < 8; ++r) {
        int grow = r0 + r;
        int mesh = grow / F, face = grow % F;
        int p = permIdx[face];
        qh[(size_t)grow * C + tid] = aq[r] * scale;
        float ko = __shfl_xor(ak[r], 1);
        float vo = __shfl_xor(av[r], 1);
        if ((tid & 1) == 0) {
            unsigned int pk = (unsigned int)f2bu(ak[r]) | ((unsigned int)f2bu(ko) << 16);
            unsigned int pv = (unsigned int)f2bu(av[r]) | ((unsigned int)f2bu(vo) << 16);
            kh0p[((size_t)mesh * F + p) * 64 + (tid >> 1)] = pk;
            vh0p[((size_t)mesh * F + p) * 64 + (tid >> 1)] = pv;
        }
    }
}

// ---------------------------------------------------------------- K3: persistent push-flood, suffix fused.
// Thread = (half, s, h): state for query pos = s*72+bi, head h; registers hold qv + online
// softmax (m,l,acc). State accumulates BOTH suffix keys (initial K/V from kh0p/vh0p, immutable,
// self-paced with a deadline schedule) AND prefix rings (new K/V via kvK/kvV agent atomics +
// LDS staging, post-barrier). Softmax is key-order invariant -> exact. Pacing fills the
// barrier-idle time with dense VALU work (keeps clocks up).
__global__ __launch_bounds__(NFT, 1) void k_flood4(
        const int* __restrict__ ringStart, const int* __restrict__ invPerm,
        const int* __restrict__ startOfPos, const int* __restrict__ levOfPos,
        const float* __restrict__ qh_all, float* __restrict__ cur,
        const unsigned int* __restrict__ kh0p, const unsigned int* __restrict__ vh0p,
        unsigned int* __restrict__ kvK, unsigned int* __restrict__ kvV,
        const float* __restrict__ Wk, const float* __restrict__ Wv, const float* __restrict__ Wo,
        int* gcount) {
    __shared__ __align__(16) float sK[MAXRING * C];   // staged ring K (fp32)
    __shared__ __align__(16) float sV[MAXRING * C];
    __shared__ __align__(16) float sP[2][C];
    __shared__ __align__(16) float sNew[2][C];
    __shared__ float mrg[2][H][18];

    int bx = blockIdx.x, tid = threadIdx.x;
    int mesh = bx & 1, bi = bx >> 1;                  // bi in [0,72)
    int half = tid >> 8, r = tid & 255, s = r >> 3, h = r & 7;
    int pos = s * NFBM + bi;
    int face = invPerm[pos];
    int mylv = levOfPos[pos];
    int rsq = startOfPos[pos];
    // suffix range [rsq, F) split between halves
    int mid = rsq + (((F - rsq) / 2 + 3) & ~3);
    if (mid > F) mid = F;
    int cur_s = half ? mid : rsq;
    int end_s = half ? F : mid;

    size_t qrow = ((size_t)mesh * F + face) * C + (h << 4);
    float qv[16];
    #pragma unroll
    for (int d = 0; d < 16; ++d) qv[d] = qh_all[qrow + d];
    float sm = -1e30f, sl = 0.f;
    float sacc[16];
    #pragma unroll
    for (int d = 0; d < 16; ++d) sacc[d] = 0.f;

    const unsigned int* K0 = kh0p + (size_t)mesh * F * 64 + h * 8;
    const unsigned int* V0 = vh0p + (size_t)mesh * F * 64 + h * 8;

    auto suffix_run = [&](int quota) {
        int n = end_s - cur_s;
        if (n > quota) n = quota;
        if (n <= 0) return;
        for (int i = 0; i < n; ++i) {
            const unsigned int* kb_ = K0 + (size_t)(cur_s + i) * 64;
            const unsigned int* vb_ = V0 + (size_t)(cur_s + i) * 64;
            uint4 ka = *(const uint4*)kb_;
            uint4 kb = *(const uint4*)(kb_ + 4);
            uint4 va = *(const uint4*)vb_;
            uint4 vb = *(const uint4*)(vb_ + 4);
            float sc;
            sc = qv[0] * LOF(ka.x);          sc = fmaf(qv[1],  HIF(ka.x), sc);
            sc = fmaf(qv[2],  LOF(ka.y), sc); sc = fmaf(qv[3],  HIF(ka.y), sc);
            sc = fmaf(qv[4],  LOF(ka.z), sc); sc = fmaf(qv[5],  HIF(ka.z), sc);
            sc = fmaf(qv[6],  LOF(ka.w), sc); sc = fmaf(qv[7],  HIF(ka.w), sc);
            sc = fmaf(qv[8],  LOF(kb.x), sc); sc = fmaf(qv[9],  HIF(kb.x), sc);
            sc = fmaf(qv[10], LOF(kb.y), sc); sc = fmaf(qv[11], HIF(kb.y), sc);
            sc = fmaf(qv[12], LOF(kb.z), sc); sc = fmaf(qv[13], HIF(kb.z), sc);
            sc = fmaf(qv[14], LOF(kb.w), sc); sc = fmaf(qv[15], HIF(kb.w), sc);
            float mn = fmaxf(sm, sc);
            float ce = __expf(sm - mn), pe = __expf(sc - mn);
            sl = sl * ce + pe;
            sm = mn;
            sacc[0]  = sacc[0]  * ce + pe * LOF(va.x);  sacc[1]  = sacc[1]  * ce + pe * HIF(va.x);
            sacc[2]  = sacc[2]  * ce + pe * LOF(va.y);  sacc[3]  = sacc[3]  * ce + pe * HIF(va.y);
            sacc[4]  = sacc[4]  * ce + pe * LOF(va.z);  sacc[5]  = sacc[5]  * ce + pe * HIF(va.z);
            sacc[6]  = sacc[6]  * ce + pe * LOF(va.w);  sacc[7]  = sacc[7]  * ce + pe * HIF(va.w);
            sacc[8]  = sacc[8]  * ce + pe * LOF(vb.x);  sacc[9]  = sacc[9]  * ce + pe * HIF(vb.x);
            sacc[10] = sacc[10] * ce + pe * LOF(vb.y);  sacc[11] = sacc[11] * ce + pe * HIF(vb.y);
            sacc[12] = sacc[12] * ce + pe * LOF(vb.z);  sacc[13] = sacc[13] * ce + pe * HIF(vb.z);
            sacc[14] = sacc[14] * ce + pe * LOF(vb.w);  sacc[15] = sacc[15] * ce + pe * HIF(vb.w);
        }
        cur_s += n;
    };

    for (int lv = 0; lv < NLV; ++lv) {
        int rs = ringStart[lv], re = ringStart[lv + 1], ring = re - rs;

        // ---------- catch-up: states finalizing this round finish their suffix
        if (mylv == lv) suffix_run(1 << 28);

        // ---------- finalize owned queries in [rs, re)
        int s_min = (rs > bi) ? (rs - bi + NFBM - 1) / NFBM : 0;
        int s_max = (re - 1 >= bi) ? (re - 1 - bi) / NFBM : -1;
        int nf = s_max - s_min + 1;                   // block-uniform, <= 2
        bool fin = (pos >= rs) && (pos < re);
        if (nf > 0) {
            if (fin && half == 1) {
                float* p = mrg[s - s_min][h];
                p[0] = sm; p[1] = sl;
                #pragma unroll
                for (int d = 0; d < 16; ++d) p[2 + d] = sacc[d];
            }
            __syncthreads();
            if (fin && half == 0) {
                const float* p = mrg[s - s_min][h];
                float mo = p[0], lo = p[1];
                float mn = fmaxf(sm, mo);
                float ca = __expf(sm - mn), cb = __expf(mo - mn);
                float lm = sl * ca + lo * cb;
                float inv = 1.f / lm;
                int slot = s - s_min;
                #pragma unroll
                for (int d = 0; d < 16; ++d)
                    sP[slot][(h << 4) + d] = (sacc[d] * ca + p[2 + d] * cb) * inv;
            }
            __syncthreads();
            // Wo projection + residual
            for (int it = tid; it < nf * C; it += NFT) {
                int qq = it >> 7, ch = it & 127;
                int fpos = (s_min + qq) * NFBM + bi;
                int ff = invPerm[fpos];
                const float* pr = sP[qq];
                float o = 0.f;
                for (int k = 0; k < C; k += 4) {
                    float4 pv = *(const float4*)&pr[k];
                    o = fmaf(pv.x, Wo[(k + 0) * C + ch], o);
                    o = fmaf(pv.y, Wo[(k + 1) * C + ch], o);
                    o = fmaf(pv.z, Wo[(k + 2) * C + ch], o);
                    o = fmaf(pv.w, Wo[(k + 3) * C + ch], o);
                }
                size_t rw = ((size_t)mesh * F + ff) * C + ch;
                float nv = cur[rw] + o;
                cur[rw] = nv;
                sNew[qq][ch] = nv;
            }
            __syncthreads();
            // Wk/Wv projection -> packed-bf16 agent stores (pos-major)
            for (int it = tid; it < nf * 128; it += NFT) {
                int qq = it >> 7, cc = it & 127;
                bool isV = cc >= 64;
                int u = cc & 63, ch0 = u * 2;
                const float* W = isV ? Wv : Wk;
                const float* nr = sNew[qq];
                float a0 = 0.f, a1 = 0.f;
                for (int k = 0; k < C; k += 4) {
                    float4 pv = *(const float4*)&nr[k];
                    a0 = fmaf(pv.x, W[(k + 0) * C + ch0], a0);
                    a0 = fmaf(pv.y, W[(k + 1) * C + ch0], a0);
                    a0 = fmaf(pv.z, W[(k + 2) * C + ch0], a0);
                    a0 = fmaf(pv.w, W[(k + 3) * C + ch0], a0);
                    a1 = fmaf(pv.x, W[(k + 0) * C + ch0 + 1], a1);
                    a1 = fmaf(pv.y, W[(k + 1) * C + ch0 + 1], a1);
                    a1 = fmaf(pv.z, W[(k + 2) * C + ch0 + 1], a1);
                    a1 = fmaf(pv.w, W[(k + 3) * C + ch0 + 1], a1);
                }
                unsigned int pk = (unsigned int)f2bu(a0) | ((unsigned int)f2bu(a1) << 16);
                int fpos = (s_min + qq) * NFBM + bi;
                unsigned int* dst = (isV ? kvV : kvK) + ((size_t)mesh * F + fpos) * 64 + u;
                __hip_atomic_store(dst, pk, __ATOMIC_RELAXED, __HIP_MEMORY_SCOPE_AGENT);
            }
        }

        // ---------- pacing: future states chip away at suffix (overlaps other blocks' finalize)
        if (mylv > lv) {
            int rem = end_s - cur_s;
            if (rem > 0) {
                int rl = mylv - lv;
                int quota = (rem + rl - 1) / rl;
                if (quota < CHUNK_MIN) quota = CHUNK_MIN;
                suffix_run(quota);
            }
        }
        if (lv == NLV - 1) break;

        // ---------- grid barrier (syncthreads drains stores before arrival)
        __syncthreads();
        if (tid == 0) {
            __hip_atomic_fetch_add(gcount, 1, __ATOMIC_RELAXED, __HIP_MEMORY_SCOPE_AGENT);
            int target = NFB * (lv + 1);
            while (__hip_atomic_load(gcount, __ATOMIC_RELAXED, __HIP_MEMORY_SCOPE_AGENT) < target)
                __builtin_amdgcn_s_sleep(2);
        }
        __syncthreads();

        // ---------- stage ring K/V (bf16 -> fp32 LDS), accumulate into pending states
        int maxPos = (QPB - 1) * NFBM + bi;
        if (maxPos >= re) {                           // block-uniform: any pending?
            for (int i = tid; i < ring * 64; i += NFT) {
                int kk = i >> 6, u = i & 63;
                size_t src = ((size_t)mesh * F + rs + kk) * 64 + u;
                unsigned int a = __hip_atomic_load(&kvK[src], __ATOMIC_RELAXED, __HIP_MEMORY_SCOPE_AGENT);
                unsigned int b = __hip_atomic_load(&kvV[src], __ATOMIC_RELAXED, __HIP_MEMORY_SCOPE_AGENT);
                sK[kk * C + 2 * u]     = LOF(a);
                sK[kk * C + 2 * u + 1] = HIF(a);
                sV[kk * C + 2 * u]     = LOF(b);
                sV[kk * C + 2 * u + 1] = HIF(b);
            }
            __syncthreads();
            if (pos >= re) {                          // pending states only
                int k0 = half ? (ring >> 1) : 0;
                int k1 = half ? ring : (ring >> 1);
                for (int kk = k0; kk < k1; ++kk) {
                    const float4* kp = (const float4*)&sK[kk * C + (h << 4)];
                    float4 a0 = kp[0], a1 = kp[1], a2 = kp[2], a3 = kp[3];
                    float sc = qv[0] * a0.x;
                    sc = fmaf(qv[1], a0.y, sc);  sc = fmaf(qv[2], a0.z, sc);  sc = fmaf(qv[3], a0.w, sc);
                    sc = fmaf(qv[4], a1.x, sc);  sc = fmaf(qv[5], a1.y, sc);  sc = fmaf(qv[6], a1.z, sc);
                    sc = fmaf(qv[7], a1.w, sc);  sc = fmaf(qv[8], a2.x, sc);  sc = fmaf(qv[9], a2.y, sc);
                    sc = fmaf(qv[10], a2.z, sc); sc = fmaf(qv[11], a2.w, sc); sc = fmaf(qv[12], a3.x, sc);
                    sc = fmaf(qv[13], a3.y, sc); sc = fmaf(qv[14], a3.z, sc); sc = fmaf(qv[15], a3.w, sc);
                    float mn = fmaxf(sm, sc);
                    float c = __expf(sm - mn), p = __expf(sc - mn);
                    sl = sl * c + p;
                    sm = mn;
                    const float4* vp = (const float4*)&sV[kk * C + (h << 4)];
                    float4 b0 = vp[0], b1 = vp[1], b2 = vp[2], b3 = vp[3];
                    sacc[0]  = sacc[0]  * c + p * b0.x;  sacc[1]  = sacc[1]  * c + p * b0.y;
                    sacc[2]  = sacc[2]  * c + p * b0.z;  sacc[3]  = sacc[3]  * c + p * b0.w;
                    sacc[4]  = sacc[4]  * c + p * b1.x;  sacc[5]  = sacc[5]  * c + p * b1.y;
                    sacc[6]  = sacc[6]  * c + p * b1.z;  sacc[7]  = sacc[7]  * c + p * b1.w;
                    sacc[8]  = sacc[8]  * c + p * b2.x;  sacc[9]  = sacc[9]  * c + p * b2.y;
                    sacc[10] = sacc[10] * c + p * b2.z;  sacc[11] = sacc[11] * c + p * b2.w;
                    sacc[12] = sacc[12] * c + p * b3.x;  sacc[13] = sacc[13] * c + p * b3.y;
                    sacc[14] = sacc[14] * c + p * b3.z;  sacc[15] = sacc[15] * c + p * b3.w;
                }
            }
        }
        // next round's finalize __syncthreads precedes any sK/sV overwrite
    }
}

// ---------------------------------------------------------------- K4: MLP + sigmoid, 4 rows/block
__global__ __launch_bounds__(256) void k_mlp(
        const float* __restrict__ cur,
        const float* __restrict__ W1, const float* __restrict__ b1,
        const float* __restrict__ W2, const float* __restrict__ b2,
        const float* __restrict__ W3, const float* __restrict__ b3,
        const float* __restrict__ W4, const float* __restrict__ b4,
        const float* __restrict__ W5, const float* __restrict__ b5,
        float* __restrict__ out_scores) {
    __shared__ __align__(16) float sIn[4][C];
    __shared__ __align__(16) float sA[4][WID];
    __shared__ __align__(16) float sB[4][WID];
    int tid = threadIdx.x;
    int r0 = blockIdx.x * 4;
    for (int i = tid; i < 4 * C; i += 256) sIn[i >> 7][i & 127] = cur[(size_t)r0 * C + i];
    __syncthreads();
    {
        float a[4];
        #pragma unroll
        for (int r = 0; r < 4; ++r) a[r] = 0.f;
        for (int k = 0; k < C; k += 4) {
            float w0 = W1[(k + 0) * WID + tid], w1 = W1[(k + 1) * WID + tid];
            float w2 = W1[(k + 2) * WID + tid], w3 = W1[(k + 3) * WID + tid];
            #pragma unroll
            for (int r = 0; r < 4; ++r) {
                float4 xv = *(const float4*)&sIn[r][k];
                a[r] = fmaf(xv.x, w0, fmaf(xv.y, w1, fmaf(xv.z, w2, fmaf(xv.w, w3, a[r]))));
            }
        }
        float bias = b1[tid];
        #pragma unroll
        for (int r = 0; r < 4; ++r) sA[r][tid] = fmaxf(a[r] + bias, 0.f);
    }
    __syncthreads();
    {
        float a[4];
        #pragma unroll
        for (int r = 0; r < 4; ++r) a[r] = 0.f;
        for (int k = 0; k < WID; k += 4) {
            float w0 = W2[(k + 0) * WID + tid], w1 = W2[(k + 1) * WID + tid];
            float w2 = W2[(k + 2) * WID + tid], w3 = W2[(k + 3) * WID + tid];
            #pragma unroll
            for (int r = 0; r < 4; ++r) {
                float4 xv = *(const float4*)&sA[r][k];
                a[r] = fmaf(xv.x, w0, fmaf(xv.y, w1, fmaf(xv.z, w2, fmaf(xv.w, w3, a[r]))));
            }
        }
        float bias = b2[tid];
        #pragma unroll
        for (int r = 0; r < 4; ++r) sB[r][tid] = fmaxf(a[r] + bias, 0.f);
    }
    __syncthreads();
    {
        float a[4];
        #pragma unroll
        for (int r = 0; r < 4; ++r) a[r] = 0.f;
        for (int k = 0; k < WID; k += 4) {
            float w0 = W3[(k + 0) * WID + tid], w1 = W3[(k + 1) * WID + tid];
            float w2 = W3[(k + 2) * WID + tid], w3 = W3[(k + 3) * WID + tid];
            #pragma unroll
            for (int r = 0; r < 4; ++r) {
                float4 xv = *(const float4*)&sB[r][k];
                a[r] = fmaf(xv.x, w0, fmaf(xv.y, w1, fmaf(xv.z, w2, fmaf(xv.w, w3, a[r]))));
            }
        }
        float bias = b3[tid];
        #pragma unroll
        for (int r = 0; r < 4; ++r) sA[r][tid] = fmaxf(a[r] + bias, 0.f);
    }
    __syncthreads();
    {
        float a[4];
        #pragma unroll
        for (int r = 0; r < 4; ++r) a[r] = 0.f;
        for (int k = 0; k < WID; k += 4) {
            float w0 = W4[(k + 0) * WID + tid], w1 = W4[(k + 1) * WID + tid];
            float w2 = W4[(k + 2) * WID + tid], w3 = W4[(k + 3) * WID + tid];
            #pragma unroll
            for (int r = 0; r < 4; ++r) {
                float4 xv = *(const float4*)&sA[r][k];
                a[r] = fmaf(xv.x, w0, fmaf(xv.y, w1, fmaf(xv.z, w2, fmaf(xv.w, w3, a[r]))));
            }
        }
        float bias = b4[tid];
        #pragma unroll
        for (int r = 0; r < 4; ++r) sB[r][tid] = fmaxf(a[r] + bias, 0.f);
    }
    __syncthreads();
    if (tid < 4) {
        float a = b5[0];
        for (int k = 0; k < WID; ++k) a = fmaf(sB[tid][k], W5[k], a);
        out_scores[r0 + tid] = 1.f / (1.f + __expf(-a));
    }
}

// ---------------------------------------------------------------- K5: cur[B,F,C] -> out0[B,C,F]
__global__ void k_transpose_out(const float* __restrict__ cur, float* __restrict__ out) {
    __shared__ float tile[32][33];
    int b = blockIdx.z;
    int f0 = blockIdx.x * 32, c0 = blockIdx.y * 32;
    int tx = threadIdx.x, ty = threadIdx.y;
    #pragma unroll
    for (int i = 0; i < 4; ++i) {
        int f = f0 + ty + i * 8;
        tile[ty + i * 8][tx] = cur[((size_t)b * F + f) * C + c0 + tx];
    }
    __syncthreads();
    #pragma unroll
    for (int i = 0; i < 4; ++i) {
        int c = c0 + ty + i * 8;
        out[((size_t)b * C + c) * F + f0 + tx] = tile[tx][ty + i * 8];
    }
}

// ----------------------------------------------------------------
extern "C" void kernel_launch(void* const* d_in, const int* in_sizes, int n_in,
                              void* d_out, int out_size, void* d_ws, size_t ws_size,
                              hipStream_t stream) {
    const size_t n = (size_t)NB * F * C;          // 589824
    float* cur  = (float*)d_ws;
    float* qh   = cur + n;
    float* wbuf = qh + n;                         // fp32 weights, 296193 (+3 pad)
    unsigned int* kh0p = (unsigned int*)(wbuf + 296196); // initial K packed [mesh][pos][64]
    unsigned int* vh0p = kh0p + (size_t)NB * F * 64;
    unsigned int* kvK  = vh0p + (size_t)NB * F * 64;     // new K/V comms (finalized only)
    unsigned int* kvV  = kvK + (size_t)NB * F * 64;
    int* permIdx    = (int*)(kvV + (size_t)NB * F * 64);
    int* invPerm    = permIdx + F;
    int* startOfPos = invPerm + F;
    int* levOfPos   = startOfPos + F;
    int* ringStartD = levOfPos + F;
    int* flag       = ringStartD + NLV + 1;
    int* gcount     = flag + 1;

    const int oWq = 0,       oWk = 16384,  oWv = 32768,  oWo = 49152;
    const int oW1 = 65536,   oB1 = 98304;
    const int oW2 = 98560,   oB2 = 164096;
    const int oW3 = 164352,  oB3 = 229888;
    const int oW4 = 230144,  oB4 = 295680;
    const int oW5 = 295936,  oB5 = 296192;
    const int wtot = 296193;

    WSegs segs = {{
        { d_in[1],  oWq, 16384 }, { d_in[2],  oWk, 16384 },
        { d_in[3],  oWv, 16384 }, { d_in[4],  oWo, 16384 },
        { d_in[5],  oW1, 32768 }, { d_in[6],  oB1, 256 },
        { d_in[7],  oW2, 65536 }, { d_in[8],  oB2, 256 },
        { d_in[9],  oW3, 65536 }, { d_in[10], oB3, 256 },
        { d_in[11], oW4, 65536 }, { d_in[12], oB4, 256 },
        { d_in[13], oW5, 256 },   { d_in[14], oB5, 1 },
    }};

    float* out0 = (float*)d_out;                  // [B,C,F] fp32
    float* out1 = out0 + (size_t)NB * C * F;      // [B,F,1] fp32

    k_detect<<<1, 256, 0, stream>>>(d_in[0], flag);
    k_perm<<<1, 256, 0, stream>>>(permIdx, invPerm, startOfPos, levOfPos, ringStartD, gcount);
    k_convert<<<(wtot + 255) / 256, 256, 0, stream>>>(segs, flag, wbuf, wtot);
    k_transpose_in<<<dim3(F / 32, C / 32, NB), dim3(32, 8), 0, stream>>>(d_in[0], flag, cur);
    k_proj_init<<<(NB * F) / 8, 128, 0, stream>>>(cur, permIdx, wbuf + oWq, wbuf + oWk, wbuf + oWv,
                                                  qh, kh0p, vh0p);
    k_flood4<<<NFB, NFT, 0, stream>>>(ringStartD, invPerm, startOfPos, levOfPos, qh, cur,
                                      kh0p, vh0p, kvK, kvV,
                                      wbuf + oWk, wbuf + oWv, wbuf + oWo, gcount);
    k_mlp<<<(NB * F) / 4, 256, 0, stream>>>(cur, wbuf + oW1, wbuf + oB1, wbuf + oW2, wbuf + oB2,
                                            wbuf + oW3, wbuf + oB3, wbuf + oW4, wbuf + oB4,
                                            wbuf + oW5, wbuf + oB5, out1);
    k_transpose_out<<<dim3(F / 32, C / 32, NB), dim3(32, 8), 0, stream>>>(cur, out0);
}